// Round 12
// baseline (124.804 us; speedup 1.0000x reference)
//
#include <hip/hip_runtime.h>

// chamfer(gt[4,8192,3], rec[4,8192,3]) + mean KL over mean/logvar [4,256,64].
// Never materialize the 268M distance tensor. min_y ||x-y||^2 =
// x^2 + min_y (y^2 - 2 x.y): prescale x'=-2x (3 FMA/pair), y^2 computed once
// per y and amortized over P=8 x-points/thread. y reads are wave-uniform ->
// scalar/SMEM (or VMEM L1 broadcast) path: NO LDS, no staging barrier.
// Cross-chunk reduction via disjoint partial stores (no atomics, no init
// kernel). 2 kernels total.

#define NPTS   8192
#define BATCH  4
#define CHUNK  256
#define NCHUNK 32     // 8192 / 256
#define P      8      // x-points per thread
#define XTILE  2048   // 256 threads * P
#define NTILE  4      // 8192 / 2048
#define FLT_BIG 3.402823466e38f

// grid = NTILE*BATCH*NCHUNK*2 = 4*4*32*2 = 1024 blocks (4/CU, 16 waves/CU).
// Inner iter (4 y): 12 uniform scalar loads + {12 VALU y^2, 96 FMA, 16 min3}
// per 32 pairs = 3.875 VALU/pair.
__global__ __launch_bounds__(256) void chamfer_kernel(
    const float* __restrict__ gt, const float* __restrict__ rec,
    float* __restrict__ pmin, float* __restrict__ out) {
  int bx    = blockIdx.x;
  int dir   = bx & 1;
  int chunk = (bx >> 1) & (NCHUNK - 1);
  int b     = (bx >> 6) & (BATCH - 1);
  int tile  = (bx >> 8) & (NTILE - 1);
  const float* xs = dir ? rec : gt;
  const float* ys = dir ? gt : rec;

  int tid = threadIdx.x;
  int xoff = tile * XTILE + tid;            // within-batch x index
  float ax[P], ay[P], az[P], mn[P];
#pragma unroll
  for (int k = 0; k < P; ++k) {
    const float* p = xs + (b * NPTS + xoff + k * 256) * 3;
    ax[k] = -2.0f * p[0];
    ay[k] = -2.0f * p[1];
    az[k] = -2.0f * p[2];
    mn[k] = FLT_BIG;
  }

  // y base for this (batch, chunk): addresses wave-uniform.
  const float* yp = ys + (b * NPTS + chunk * CHUNK) * 3;

  for (int m = 0; m < CHUNK; m += 4) {
    const float* q = yp + m * 3;           // 48B step, 16B-aligned: 3x dwordx4
    float y0x = q[0],  y0y = q[1],  y0z = q[2];
    float y1x = q[3],  y1y = q[4],  y1z = q[5];
    float y2x = q[6],  y2y = q[7],  y2z = q[8];
    float y3x = q[9],  y3y = q[10], y3z = q[11];
    float q0 = fmaf(y0z, y0z, fmaf(y0y, y0y, y0x * y0x));
    float q1 = fmaf(y1z, y1z, fmaf(y1y, y1y, y1x * y1x));
    float q2 = fmaf(y2z, y2z, fmaf(y2y, y2y, y2x * y2x));
    float q3 = fmaf(y3z, y3z, fmaf(y3y, y3y, y3x * y3x));
#pragma unroll
    for (int k = 0; k < P; ++k) {
      float e0 = fmaf(ax[k], y0x, fmaf(ay[k], y0y, fmaf(az[k], y0z, q0)));
      float e1 = fmaf(ax[k], y1x, fmaf(ay[k], y1y, fmaf(az[k], y1z, q1)));
      float e2 = fmaf(ax[k], y2x, fmaf(ay[k], y2y, fmaf(az[k], y2z, q2)));
      float e3 = fmaf(ax[k], y3x, fmaf(ay[k], y3y, fmaf(az[k], y3z, q3)));
      mn[k] = fminf(fminf(mn[k], e0), e1);   // -> v_min3_f32
      mn[k] = fminf(fminf(mn[k], e2), e3);
    }
  }

  // pmin[(dir*NCHUNK+chunk)][b*NPTS + xoff + k*256] — disjoint across blocks
  float* dst = pmin + (dir * NCHUNK + chunk) * (BATCH * NPTS) + b * NPTS + xoff;
#pragma unroll
  for (int k = 0; k < P; ++k) dst[k * 256] = mn[k];

  if (bx == 0 && tid == 0) out[0] = 0.0f;  // consumed by finalize (next kernel)
}

// 256 blocks x 256 = 65536 threads: one (dir, point) each -> reduce 32 chunk
// partials + add x^2; plus one KL element each. Block-reduce, atomicAdd.
__global__ __launch_bounds__(256) void finalize_kernel(
    const float* __restrict__ gt, const float* __restrict__ rec,
    const float* __restrict__ pmin,
    const float* __restrict__ mean, const float* __restrict__ logvar,
    float* __restrict__ out) {
  int t   = blockIdx.x * 256 + threadIdx.x;   // 0..65535
  int d   = t >> 15;                          // direction
  int idx = t & 32767;                        // b*8192 + i

  float mv = FLT_BIG;
  const float* pp = pmin + d * (NCHUNK * BATCH * NPTS) + idx;
#pragma unroll 8
  for (int c = 0; c < NCHUNK; ++c) mv = fminf(mv, pp[c * (BATCH * NPTS)]);

  const float* xsrc = d ? rec : gt;
  const float* p = xsrc + idx * 3;
  float x2 = fmaf(p[0], p[0], fmaf(p[1], p[1], p[2] * p[2]));
  float s = (x2 + mv) * (1.0f / 32768.0f);    // mean over B*N per direction

  float mm = mean[t], lv = logvar[t];         // exactly 65536 KL elements
  s += 0.125f * (fmaf(mm, mm, expf(lv) - 1.0f) - lv);  // 0.5 * mean-over-B

  for (int off = 32; off > 0; off >>= 1) s += __shfl_down(s, off);
  __shared__ float wsum[4];
  int lane = threadIdx.x & 63, w = threadIdx.x >> 6;
  if (lane == 0) wsum[w] = s;
  __syncthreads();
  if (threadIdx.x == 0) atomicAdd(out, wsum[0] + wsum[1] + wsum[2] + wsum[3]);
}

extern "C" void kernel_launch(void* const* d_in, const int* in_sizes, int n_in,
                              void* d_out, int out_size, void* d_ws, size_t ws_size,
                              hipStream_t stream) {
  const float* gt     = (const float*)d_in[0];
  const float* rec    = (const float*)d_in[1];
  const float* mean   = (const float*)d_in[2];
  const float* logvar = (const float*)d_in[3];
  float* out  = (float*)d_out;
  float* pmin = (float*)d_ws;   // 2 * 32 * 4 * 8192 * 4B = 8 MiB

  chamfer_kernel<<<1024, 256, 0, stream>>>(gt, rec, pmin, out);
  finalize_kernel<<<256, 256, 0, stream>>>(gt, rec, pmin, mean, logvar, out);
}

// Round 13
// 112.589 us; speedup vs baseline: 1.1085x; 1.1085x over previous
//
#include <hip/hip_runtime.h>

// chamfer(gt[4,8192,3], rec[4,8192,3]) + mean KL over mean/logvar [4,256,64].
// R13: back to the VALIDATED LDS-broadcast structure (R5 matched its model;
// global-uniform reads in R12 regressed to 63us). Fixes R5's LDS-pipe
// oversubscription: SoA LDS with y^2 precomputed at staging -> 4 uniform
// ds_read_b64 per 2y (~32cyc) vs 64-112cyc VALU. P=8 x/thread. e-pairs as
// float2 elementwise-fma to coax v_pk_fma_f32 (2 VALU/pair -> ~14us floor;
// falls back to scalar = no worse than 24us floor).

typedef float v2f __attribute__((ext_vector_type(2)));

#define NPTS   8192
#define BATCH  4
#define CHUNK  256
#define NCHUNK 32     // 8192 / 256
#define P      8      // x-points per thread
#define XTILE  2048   // 256 threads * P
#define NTILE  4      // 8192 / 2048
#define FLT_BIG 3.402823466e38f

// grid = 2 dirs * 32 chunks * 4 batches * 4 tiles = 1024 blocks
// (4 blocks/CU, 16 waves/CU guaranteed by __launch_bounds__(256,4)).
__global__ __launch_bounds__(256, 4) void chamfer_kernel(
    const float* __restrict__ gt, const float* __restrict__ rec,
    float* __restrict__ pmin, float* __restrict__ out) {
  __shared__ float syx[CHUNK], syy[CHUNK], syz[CHUNK], syq[CHUNK];  // 4 KiB SoA

  int bx    = blockIdx.x;
  int dir   = bx & 1;
  int chunk = (bx >> 1) & (NCHUNK - 1);
  int b     = (bx >> 6) & (BATCH - 1);
  int tile  = (bx >> 8) & (NTILE - 1);
  const float* xs = dir ? rec : gt;
  const float* ys = dir ? gt : rec;

  int tid = threadIdx.x;

  // Stage y-chunk to SoA LDS with ||y||^2 precomputed (one point per thread;
  // writes tid-linear -> conflict-free).
  {
    const float* q = ys + (b * NPTS + chunk * CHUNK + tid) * 3;
    float yx = q[0], yy = q[1], yz = q[2];
    syx[tid] = yx;
    syy[tid] = yy;
    syz[tid] = yz;
    syq[tid] = fmaf(yz, yz, fmaf(yy, yy, yx * yx));
  }

  // x' = -2x, pre-splatted into float2 for packed FMA.
  int xoff = tile * XTILE + tid;            // within-batch x index
  v2f ax2[P], ay2[P], az2[P];
  float mn[P];
#pragma unroll
  for (int k = 0; k < P; ++k) {
    const float* p = xs + (b * NPTS + xoff + k * 256) * 3;
    float ax = -2.0f * p[0], ay = -2.0f * p[1], az = -2.0f * p[2];
    ax2[k] = (v2f){ax, ax};
    ay2[k] = (v2f){ay, ay};
    az2[k] = (v2f){az, az};
    mn[k] = FLT_BIG;
  }

  __syncthreads();

  // Inner loop per 2y: 4 uniform ds_read_b64 (broadcast) + per-k
  // {3 pk_fma + 1 min3} = 2 VALU ops/pair (if packed forms).
#pragma unroll 4
  for (int m = 0; m < CHUNK; m += 2) {
    v2f yx = *(const v2f*)&syx[m];   // 8B-aligned (m even)
    v2f yy = *(const v2f*)&syy[m];
    v2f yz = *(const v2f*)&syz[m];
    v2f yq = *(const v2f*)&syq[m];
#pragma unroll
    for (int k = 0; k < P; ++k) {
      v2f e = __builtin_elementwise_fma(ax2[k], yx,
              __builtin_elementwise_fma(ay2[k], yy,
              __builtin_elementwise_fma(az2[k], yz, yq)));
      mn[k] = fminf(mn[k], fminf(e.x, e.y));   // -> v_min3_f32
    }
  }

  // pmin[(dir*NCHUNK+chunk)][b*NPTS + xoff + k*256] — disjoint across blocks
  float* dst = pmin + (dir * NCHUNK + chunk) * (BATCH * NPTS) + b * NPTS + xoff;
#pragma unroll
  for (int k = 0; k < P; ++k) dst[k * 256] = mn[k];

  if (bx == 0 && tid == 0) out[0] = 0.0f;  // consumed by finalize (next kernel)
}

// 256 blocks x 256 = 65536 threads: one (dir, point) each -> reduce 32 chunk
// partials + add x^2; plus one KL element each. Block-reduce, atomicAdd.
// (Structure validated twice: absmax 0.0 in R5 and R12.)
__global__ __launch_bounds__(256) void finalize_kernel(
    const float* __restrict__ gt, const float* __restrict__ rec,
    const float* __restrict__ pmin,
    const float* __restrict__ mean, const float* __restrict__ logvar,
    float* __restrict__ out) {
  int t   = blockIdx.x * 256 + threadIdx.x;   // 0..65535
  int d   = t >> 15;                          // direction
  int idx = t & 32767;                        // b*8192 + i

  float mv = FLT_BIG;
  const float* pp = pmin + d * (NCHUNK * BATCH * NPTS) + idx;
#pragma unroll 8
  for (int c = 0; c < NCHUNK; ++c) mv = fminf(mv, pp[c * (BATCH * NPTS)]);

  const float* xsrc = d ? rec : gt;
  const float* p = xsrc + idx * 3;
  float x2 = fmaf(p[0], p[0], fmaf(p[1], p[1], p[2] * p[2]));
  float s = (x2 + mv) * (1.0f / 32768.0f);    // mean over B*N per direction

  float mm = mean[t], lv = logvar[t];         // exactly 65536 KL elements
  s += 0.125f * (fmaf(mm, mm, expf(lv) - 1.0f) - lv);  // 0.5 * mean-over-B

  for (int off = 32; off > 0; off >>= 1) s += __shfl_down(s, off);
  __shared__ float wsum[4];
  int lane = threadIdx.x & 63, w = threadIdx.x >> 6;
  if (lane == 0) wsum[w] = s;
  __syncthreads();
  if (threadIdx.x == 0) atomicAdd(out, wsum[0] + wsum[1] + wsum[2] + wsum[3]);
}

extern "C" void kernel_launch(void* const* d_in, const int* in_sizes, int n_in,
                              void* d_out, int out_size, void* d_ws, size_t ws_size,
                              hipStream_t stream) {
  const float* gt     = (const float*)d_in[0];
  const float* rec    = (const float*)d_in[1];
  const float* mean   = (const float*)d_in[2];
  const float* logvar = (const float*)d_in[3];
  float* out  = (float*)d_out;
  float* pmin = (float*)d_ws;   // 2 * 32 * 4 * 8192 * 4B = 8 MiB

  chamfer_kernel<<<1024, 256, 0, stream>>>(gt, rec, pmin, out);
  finalize_kernel<<<256, 256, 0, stream>>>(gt, rec, pmin, mean, logvar, out);
}